// Round 4
// baseline (122.763 us; speedup 1.0000x reference)
//
#include <hip/hip_runtime.h>
#include <math.h>

#define B 4
#define DEC 256
#define ENC 256
#define HDIM 512

// exp2(x*TANH_SCALE) == e^{2x};  tanh(x) = 1 - 2/(1+e^{2x})
#define TANH_SCALE 2.8853900817779268f
#define LOG2E 1.4426950408889634f

__device__ __forceinline__ float fast_exp2(float x) { return __builtin_amdgcn_exp2f(x); }
__device__ __forceinline__ float fast_rcp(float x)  { return __builtin_amdgcn_rcpf(x); }

typedef __attribute__((ext_vector_type(8))) short bf16x8;   // 8 bf16 = 4 VGPR
typedef __attribute__((ext_vector_type(4))) short bf16x4;
typedef __attribute__((ext_vector_type(4))) float f32x4;

__device__ __forceinline__ unsigned short bf16_rne(float x) {
    unsigned u = __float_as_uint(x);
    return (unsigned short)((u + 0x7FFFu + ((u >> 16) & 1u)) >> 16);
}
__device__ __forceinline__ float bf16_to_f(unsigned short h) {
    return __uint_as_float((unsigned)h << 16);
}

// Blocked-transpose W layout (shorts): ofs(m,k) = (m/16)*8192 + (k/8)*128 + (m%16)*8 + k%8
#define W_OFS(m, k) ((((long)(m) >> 4) << 13) + (((long)(k) >> 3) << 7) + (((m) & 15) << 3) + ((k) & 7))

// ---------------------------------------------------------------------------
// convert: fp32 -> bf16 hi/lo split. (unchanged)
// ---------------------------------------------------------------------------
__global__ __launch_bounds__(256) void convert_kernel(
    const float* __restrict__ enc, const float* __restrict__ dec,
    const float* __restrict__ Wmlp,
    unsigned short* __restrict__ Xh_e, unsigned short* __restrict__ Xl_e,
    unsigned short* __restrict__ Xh_d, unsigned short* __restrict__ Xl_d,
    unsigned short* __restrict__ Wh_e, unsigned short* __restrict__ Wl_e,
    unsigned short* __restrict__ Wh_d, unsigned short* __restrict__ Wl_d)
{
    const int tid = threadIdx.x, z = blockIdx.z;
    if (z < 2) {
        const float* X = z ? dec : enc;
        unsigned short* H = z ? Xh_d : Xh_e;
        unsigned short* L = z ? Xl_d : Xl_e;
        const long i8 = ((long)blockIdx.x * 256 + tid) * 8;
        float4 v0 = *(const float4*)(X + i8);
        float4 v1 = *(const float4*)(X + i8 + 4);
        float xs[8] = {v0.x, v0.y, v0.z, v0.w, v1.x, v1.y, v1.z, v1.w};
        bf16x8 hv, lv;
#pragma unroll
        for (int j = 0; j < 8; ++j) {
            unsigned short h = bf16_rne(xs[j]);
            hv[j] = (short)h;
            lv[j] = (short)bf16_rne(xs[j] - bf16_to_f(h));
        }
        *(bf16x8*)(H + i8) = hv;
        *(bf16x8*)(L + i8) = lv;
    } else {
        const float* Wsrc = Wmlp + (z == 3 ? (long)HDIM * HDIM : 0);
        unsigned short* H = (z == 3) ? Wh_d : Wh_e;
        unsigned short* L = (z == 3) ? Wl_d : Wl_e;
        const int t = blockIdx.x * 256 + tid;     // 0..65535
        const int m = t & 511;
        const int k0 = (t >> 9) << 2;             // multiple of 4
        bf16x4 hv, lv;
#pragma unroll
        for (int j = 0; j < 4; ++j) {
            float x = Wsrc[(long)(k0 + j) * 512 + m];   // coalesced reads
            unsigned short h = bf16_rne(x);
            hv[j] = (short)h;
            lv[j] = (short)bf16_rne(x - bf16_to_f(h));
        }
        const long ofs = W_OFS(m, k0);            // 4 consecutive shorts
        *(bf16x4*)(H + ofs) = hv;
        *(bf16x4*)(L + ofs) = lv;
    }
}

// ---------------------------------------------------------------------------
// proj via MFMA (unchanged): wave = 16 r x 32 m, block = 64 r x 32 m.
// ---------------------------------------------------------------------------
__global__ __launch_bounds__(256) void proj_mfma_kernel(
    const unsigned short* __restrict__ Xh_e, const unsigned short* __restrict__ Xl_e,
    const unsigned short* __restrict__ Xh_d, const unsigned short* __restrict__ Xl_d,
    const unsigned short* __restrict__ Wh_e, const unsigned short* __restrict__ Wl_e,
    const unsigned short* __restrict__ Wh_d, const unsigned short* __restrict__ Wl_d,
    const float* __restrict__ bmlp,
    float* __restrict__ ET, float* __restrict__ Dmat)
{
    const int tid = threadIdx.x;
    const int wave = tid >> 6, lane = tid & 63;
    const int z = blockIdx.z;
    const int r0w = blockIdx.x * 64 + wave * 16;
    const int m0 = blockIdx.y * 32;
    const unsigned short* Xh = z ? Xh_d : Xh_e;
    const unsigned short* Xl = z ? Xl_d : Xl_e;
    const unsigned short* Wh = z ? Wh_d : Wh_e;
    const unsigned short* Wl = z ? Wl_d : Wl_e;

    const int col = lane & 15;
    const int quad = lane >> 4;

    const unsigned short* pah = Xh + (long)(r0w + col) * 512 + quad * 8;
    const unsigned short* pal = Xl + (long)(r0w + col) * 512 + quad * 8;
    const long bofs = ((long)(m0 >> 4) << 13) + (quad << 7) + (col << 3);
    const unsigned short* pb0h = Wh + bofs;
    const unsigned short* pb0l = Wl + bofs;
    const unsigned short* pb1h = Wh + bofs + 8192;
    const unsigned short* pb1l = Wl + bofs + 8192;

    f32x4 a0h = {0.f,0.f,0.f,0.f}, a0x = {0.f,0.f,0.f,0.f};
    f32x4 a1h = {0.f,0.f,0.f,0.f}, a1x = {0.f,0.f,0.f,0.f};

    bf16x8 Ah = *(const bf16x8*)pah,  Al = *(const bf16x8*)pal;
    bf16x8 B0h = *(const bf16x8*)pb0h, B0l = *(const bf16x8*)pb0l;
    bf16x8 B1h = *(const bf16x8*)pb1h, B1l = *(const bf16x8*)pb1l;

#pragma unroll 1
    for (int k0 = 0; k0 < 512; k0 += 32) {
        bf16x8 nAh = Ah, nAl = Al, nB0h = B0h, nB0l = B0l, nB1h = B1h, nB1l = B1l;
        if (k0 + 32 < 512) {
            nAh = *(const bf16x8*)(pah + k0 + 32);
            nAl = *(const bf16x8*)(pal + k0 + 32);
            const long ko = (long)(k0 + 32) << 4;
            nB0h = *(const bf16x8*)(pb0h + ko);
            nB0l = *(const bf16x8*)(pb0l + ko);
            nB1h = *(const bf16x8*)(pb1h + ko);
            nB1l = *(const bf16x8*)(pb1l + ko);
        }
        a0h = __builtin_amdgcn_mfma_f32_16x16x32_bf16(Ah, B0h, a0h, 0, 0, 0);
        a1h = __builtin_amdgcn_mfma_f32_16x16x32_bf16(Ah, B1h, a1h, 0, 0, 0);
        a0x = __builtin_amdgcn_mfma_f32_16x16x32_bf16(Ah, B0l, a0x, 0, 0, 0);
        a1x = __builtin_amdgcn_mfma_f32_16x16x32_bf16(Ah, B1l, a1x, 0, 0, 0);
        a0x = __builtin_amdgcn_mfma_f32_16x16x32_bf16(Al, B0h, a0x, 0, 0, 0);
        a1x = __builtin_amdgcn_mfma_f32_16x16x32_bf16(Al, B1h, a1x, 0, 0, 0);
        Ah = nAh; Al = nAl; B0h = nB0h; B0l = nB0l; B1h = nB1h; B1l = nB1l;
    }

    if (z == 0) {
        const int batch = r0w >> 8;
        const int e0 = (r0w & 255) + quad * 4;
        float* base = ET + (long)batch * HDIM * ENC;
        float4 v;
        v.x = fast_exp2((a0h[0] + a0x[0]) * TANH_SCALE);
        v.y = fast_exp2((a0h[1] + a0x[1]) * TANH_SCALE);
        v.z = fast_exp2((a0h[2] + a0x[2]) * TANH_SCALE);
        v.w = fast_exp2((a0h[3] + a0x[3]) * TANH_SCALE);
        *(float4*)&base[(long)(m0 + col) * ENC + e0] = v;
        v.x = fast_exp2((a1h[0] + a1x[0]) * TANH_SCALE);
        v.y = fast_exp2((a1h[1] + a1x[1]) * TANH_SCALE);
        v.z = fast_exp2((a1h[2] + a1x[2]) * TANH_SCALE);
        v.w = fast_exp2((a1h[3] + a1x[3]) * TANH_SCALE);
        *(float4*)&base[(long)(m0 + 16 + col) * ENC + e0] = v;
    } else {
        const float bq0 = bmlp[m0 + col];
        const float bq1 = bmlp[m0 + 16 + col];
        const int r = r0w + quad * 4;
#pragma unroll
        for (int i = 0; i < 4; ++i) {
            Dmat[(long)(r + i) * HDIM + m0 + col] =
                fast_exp2((a0h[i] + a0x[i] + bq0) * TANH_SCALE);
            Dmat[(long)(r + i) * HDIM + m0 + 16 + col] =
                fast_exp2((a1h[i] + a1x[i] + bq1) * TANH_SCALE);
        }
    }
}

// ---------------------------------------------------------------------------
// FUSED attn+softmax+context v4: one block = (b, 2 decoder rows), 256 thr.
// grid (128, 1, 4) = 512 blocks -> 2 INDEPENDENT blocks per CU.
// Rationale (R3 post-mortem): v3 ran 1 block/CU; barrier-separated phases
// serialized trans-pipe rcp work (~14us chip floor) with L2 phases (~8us)
// -> VALUBusy 40%.  Two blocks/CU lets block A's rcp burst overlap block
// B's stage/GEMV memory phases.  Same math, E-prefetch depth 4.
// Phase 2: thread = (4 consecutive e, wave-private 128-m group).
// Phase 3: softmax over e for the 2 rows (all 4 waves).
// Phase 4: thread = h & h+256; enc read once per block.
// ---------------------------------------------------------------------------
__global__ __launch_bounds__(256) void attn_ctx_kernel(
    const float* __restrict__ Dmat, const float* __restrict__ ET,
    const float* __restrict__ wo,
    const float* __restrict__ enc, const unsigned char* __restrict__ extm,
    float* __restrict__ attn_out, float* __restrict__ ctx)
{
    __shared__ __align__(16) float ds[2][HDIM];        // 4KB   D rows
    __shared__ __align__(16) float wos[HDIM];          // 2KB   W_out
    __shared__ __align__(16) float p4[4][2][ENC];      // 8KB   m-group partials
    __shared__ __align__(16) float as2T[ENC][2];       // 2KB   probs, transposed
    __shared__ float redm[2][4];
    __shared__ float reds[2][4];

    const int tid = threadIdx.x;               // 0..255
    const int b = blockIdx.z, d0 = blockIdx.x * 2;
    const long g0 = (long)b * DEC + d0;

    // ---- phase 1: stage 2 D rows (contiguous 4KB) + wo ----
    ((float4*)ds)[tid] = ((const float4*)(Dmat + g0 * HDIM))[tid];
    if (tid < 128) ((float4*)wos)[tid] = ((const float4*)wo)[tid];

    const int mg = tid >> 6;          // 0..3 == wave -> m in [mg*128, mg*128+128)
    const int e4 = (tid & 63) * 4;    // 4 consecutive e per thread
    const int mbase = mg * 128;
    const float* ep = ET + (long)b * HDIM * ENC + (long)mbase * ENC + e4;

    // prefetch depth 4 (global, independent of LDS)
    float4 Eb0 = *(const float4*)(ep);
    float4 Eb1 = *(const float4*)(ep + ENC);
    float4 Eb2 = *(const float4*)(ep + 2 * ENC);
    float4 Eb3 = *(const float4*)(ep + 3 * ENC);
    __syncthreads();

    // ---- phase 2: 128-m reduction, 4 e-cols x 2 rows per thread ----
    float acc[2][4] = {};             // [r][j]
    for (int i = 0; i < 128; i += 2) {
        float4 Ea = Eb0, Eb = Eb1;
        Eb0 = Eb2; Eb1 = Eb3;
        if (i + 4 < 128) {
            Eb2 = *(const float4*)(ep + (long)(i + 4) * ENC);
            Eb3 = *(const float4*)(ep + (long)(i + 5) * ENC);
        }
        const int m = mbase + i;
        const float w0 = wos[m], w1 = wos[m + 1];
#pragma unroll
        for (int r = 0; r < 2; ++r) {
            const float dr0 = ds[r][m];
            const float dr1 = ds[r][m + 1];
#pragma unroll
            for (int j = 0; j < 4; ++j) {
                float ea = ((const float*)&Ea)[j];
                float eb = ((const float*)&Eb)[j];
                acc[r][j] = fmaf(w0, fast_rcp(fmaf(ea, dr0, 1.0f)), acc[r][j]);
                acc[r][j] = fmaf(w1, fast_rcp(fmaf(eb, dr1, 1.0f)), acc[r][j]);
            }
        }
    }
#pragma unroll
    for (int r = 0; r < 2; ++r) {
        float4 v = make_float4(acc[r][0], acc[r][1], acc[r][2], acc[r][3]);
        *(float4*)&p4[mg][r][e4] = v;
    }
    __syncthreads();

    // ---- phase 3: combine + masks + softmax (all 4 waves, e = tid) ----
    const int e = tid;
    const int wave = tid >> 6, lane = tid & 63;

    const bool pad = (enc[((long)b * ENC + e) * HDIM] == 0.0f);
    float l[2], p[2];
#pragma unroll
    for (int r = 0; r < 2; ++r) {
        float a = p4[0][r][e] + p4[1][r][e] + p4[2][r][e] + p4[3][r][e];
        const bool xm = extm[(g0 + r) * ENC + e] != 0;
        l[r] = (pad || xm) ? -__builtin_inff() : -2.0f * a;
    }
    float mx[2] = {l[0], l[1]};
#pragma unroll
    for (int off = 32; off >= 1; off >>= 1) {
#pragma unroll
        for (int r = 0; r < 2; ++r)
            mx[r] = fmaxf(mx[r], __shfl_xor(mx[r], off, 64));
    }
    if (lane == 0) { redm[0][wave] = mx[0]; redm[1][wave] = mx[1]; }
    __syncthreads();
    float s[2];
#pragma unroll
    for (int r = 0; r < 2; ++r) {
        const float gm = fmaxf(fmaxf(redm[r][0], redm[r][1]),
                               fmaxf(redm[r][2], redm[r][3]));
        p[r] = fast_exp2((l[r] - gm) * LOG2E);
        s[r] = p[r];
    }
#pragma unroll
    for (int off = 32; off >= 1; off >>= 1) {
#pragma unroll
        for (int r = 0; r < 2; ++r)
            s[r] += __shfl_xor(s[r], off, 64);
    }
    if (lane == 0) { reds[0][wave] = s[0]; reds[1][wave] = s[1]; }
    __syncthreads();
    {
        const float gs0 = reds[0][0] + reds[0][1] + reds[0][2] + reds[0][3];
        const float gs1 = reds[1][0] + reds[1][1] + reds[1][2] + reds[1][3];
        const float pr0 = p[0] * fast_rcp(gs0);
        const float pr1 = p[1] * fast_rcp(gs1);
        attn_out[(g0 + 0) * ENC + e] = pr0;
        attn_out[(g0 + 1) * ENC + e] = pr1;
        *(float2*)&as2T[e][0] = make_float2(pr0, pr1);
    }
    __syncthreads();

    // ---- phase 4: ctx GEMV, thread = (h, h+256); enc read ONCE per block ----
    const int h = tid;                              // 0..255
    const float* eh = enc + (long)b * ENC * HDIM + h;
    float ac00 = 0.f, ac01 = 0.f, ac10 = 0.f, ac11 = 0.f;  // [hpart][row]
    float eb0[8], eb1[8], nb0[8], nb1[8];
#pragma unroll
    for (int j = 0; j < 8; ++j) {
        eb0[j] = eh[(long)j * HDIM];
        eb1[j] = eh[(long)j * HDIM + 256];
    }
    for (int e0 = 0; e0 < ENC; e0 += 8) {
        if (e0 + 8 < ENC) {
#pragma unroll
            for (int j = 0; j < 8; ++j) {
                nb0[j] = eh[(long)(e0 + 8 + j) * HDIM];
                nb1[j] = eh[(long)(e0 + 8 + j) * HDIM + 256];
            }
        }
#pragma unroll
        for (int j = 0; j < 8; ++j) {
            float2 prv = *(const float2*)&as2T[e0 + j][0];   // broadcast b64
            ac00 = fmaf(prv.x, eb0[j], ac00);
            ac01 = fmaf(prv.y, eb0[j], ac01);
            ac10 = fmaf(prv.x, eb1[j], ac10);
            ac11 = fmaf(prv.y, eb1[j], ac11);
        }
#pragma unroll
        for (int j = 0; j < 8; ++j) { eb0[j] = nb0[j]; eb1[j] = nb1[j]; }
    }
    ctx[(g0 + 0) * HDIM + h]       = ac00;
    ctx[(g0 + 1) * HDIM + h]       = ac01;
    ctx[(g0 + 0) * HDIM + h + 256] = ac10;
    ctx[(g0 + 1) * HDIM + h + 256] = ac11;
}

// ---------------------------------------------------------------------------
extern "C" void kernel_launch(void* const* d_in, const int* in_sizes, int n_in,
                              void* d_out, int out_size, void* d_ws, size_t ws_size,
                              hipStream_t stream) {
    const float* dec = (const float*)d_in[0];
    const float* enc = (const float*)d_in[1];
    const unsigned char* extm = (const unsigned char*)d_in[2];
    const float* Wmlp = (const float*)d_in[3];
    const float* bmlp = (const float*)d_in[4];
    const float* Wout = (const float*)d_in[5];
    // d_in[6] = b_out: additive constant, cancels in softmax

    float* ctx = (float*)d_out;                    // [B, DEC, H]
    float* attn = ctx + (size_t)B * DEC * HDIM;    // [B, DEC, ENC]

    const size_t F = (size_t)B * DEC * HDIM;       // 524288
    float* ET = (float*)d_ws;                      // [B][H][ENC] fp32
    float* Dmat = ET + F;                          // [B*DEC][H] fp32
    unsigned short* Xh_e = (unsigned short*)(Dmat + F);
    unsigned short* Xl_e = Xh_e + F;
    unsigned short* Xh_d = Xl_e + F;
    unsigned short* Xl_d = Xh_d + F;
    unsigned short* Wh_e = Xl_d + F;               // blocked-T layout, 512*512
    unsigned short* Wl_e = Wh_e + HDIM * HDIM;
    unsigned short* Wh_d = Wl_e + HDIM * HDIM;
    unsigned short* Wl_d = Wh_d + HDIM * HDIM;

    convert_kernel<<<dim3(256, 1, 4), 256, 0, stream>>>(
        enc, dec, Wmlp, Xh_e, Xl_e, Xh_d, Xl_d, Wh_e, Wl_e, Wh_d, Wl_d);
    proj_mfma_kernel<<<dim3(16, 16, 2), 256, 0, stream>>>(
        Xh_e, Xl_e, Xh_d, Xl_d, Wh_e, Wl_e, Wh_d, Wl_d, bmlp, ET, Dmat);
    attn_ctx_kernel<<<dim3(DEC / 2, 1, B), 256, 0, stream>>>(
        Dmat, ET, Wout, enc, extm, attn, ctx);
}

// Round 5
// 110.916 us; speedup vs baseline: 1.1068x; 1.1068x over previous
//
#include <hip/hip_runtime.h>
#include <math.h>

#define B 4
#define DEC 256
#define ENC 256
#define HDIM 512

// exp2(x*TANH_SCALE) == e^{2x};  tanh(x) = 1 - 2/(1+e^{2x})
#define TANH_SCALE 2.8853900817779268f
#define LOG2E 1.4426950408889634f

__device__ __forceinline__ float fast_exp2(float x) { return __builtin_amdgcn_exp2f(x); }
__device__ __forceinline__ float fast_rcp(float x)  { return __builtin_amdgcn_rcpf(x); }

typedef __attribute__((ext_vector_type(8))) short bf16x8;   // 8 bf16 = 4 VGPR
typedef __attribute__((ext_vector_type(4))) short bf16x4;
typedef __attribute__((ext_vector_type(4))) float f32x4;

__device__ __forceinline__ unsigned short bf16_rne(float x) {
    unsigned u = __float_as_uint(x);
    return (unsigned short)((u + 0x7FFFu + ((u >> 16) & 1u)) >> 16);
}
__device__ __forceinline__ float bf16_to_f(unsigned short h) {
    return __uint_as_float((unsigned)h << 16);
}

// Blocked-transpose W layout (shorts): ofs(m,k) = (m/16)*8192 + (k/8)*128 + (m%16)*8 + k%8
#define W_OFS(m, k) ((((long)(m) >> 4) << 13) + (((long)(k) >> 3) << 7) + (((m) & 15) << 3) + ((k) & 7))

// ---------------------------------------------------------------------------
// convert: fp32 -> bf16 hi/lo split. (unchanged)
// ---------------------------------------------------------------------------
__global__ __launch_bounds__(256) void convert_kernel(
    const float* __restrict__ enc, const float* __restrict__ dec,
    const float* __restrict__ Wmlp,
    unsigned short* __restrict__ Xh_e, unsigned short* __restrict__ Xl_e,
    unsigned short* __restrict__ Xh_d, unsigned short* __restrict__ Xl_d,
    unsigned short* __restrict__ Wh_e, unsigned short* __restrict__ Wl_e,
    unsigned short* __restrict__ Wh_d, unsigned short* __restrict__ Wl_d)
{
    const int tid = threadIdx.x, z = blockIdx.z;
    if (z < 2) {
        const float* X = z ? dec : enc;
        unsigned short* H = z ? Xh_d : Xh_e;
        unsigned short* L = z ? Xl_d : Xl_e;
        const long i8 = ((long)blockIdx.x * 256 + tid) * 8;
        float4 v0 = *(const float4*)(X + i8);
        float4 v1 = *(const float4*)(X + i8 + 4);
        float xs[8] = {v0.x, v0.y, v0.z, v0.w, v1.x, v1.y, v1.z, v1.w};
        bf16x8 hv, lv;
#pragma unroll
        for (int j = 0; j < 8; ++j) {
            unsigned short h = bf16_rne(xs[j]);
            hv[j] = (short)h;
            lv[j] = (short)bf16_rne(xs[j] - bf16_to_f(h));
        }
        *(bf16x8*)(H + i8) = hv;
        *(bf16x8*)(L + i8) = lv;
    } else {
        const float* Wsrc = Wmlp + (z == 3 ? (long)HDIM * HDIM : 0);
        unsigned short* H = (z == 3) ? Wh_d : Wh_e;
        unsigned short* L = (z == 3) ? Wl_d : Wl_e;
        const int t = blockIdx.x * 256 + tid;     // 0..65535
        const int m = t & 511;
        const int k0 = (t >> 9) << 2;             // multiple of 4
        bf16x4 hv, lv;
#pragma unroll
        for (int j = 0; j < 4; ++j) {
            float x = Wsrc[(long)(k0 + j) * 512 + m];   // coalesced reads
            unsigned short h = bf16_rne(x);
            hv[j] = (short)h;
            lv[j] = (short)bf16_rne(x - bf16_to_f(h));
        }
        const long ofs = W_OFS(m, k0);            // 4 consecutive shorts
        *(bf16x4*)(H + ofs) = hv;
        *(bf16x4*)(L + ofs) = lv;
    }
}

// ---------------------------------------------------------------------------
// proj via MFMA (unchanged): wave = 16 r x 32 m, block = 64 r x 32 m.
// ---------------------------------------------------------------------------
__global__ __launch_bounds__(256) void proj_mfma_kernel(
    const unsigned short* __restrict__ Xh_e, const unsigned short* __restrict__ Xl_e,
    const unsigned short* __restrict__ Xh_d, const unsigned short* __restrict__ Xl_d,
    const unsigned short* __restrict__ Wh_e, const unsigned short* __restrict__ Wl_e,
    const unsigned short* __restrict__ Wh_d, const unsigned short* __restrict__ Wl_d,
    const float* __restrict__ bmlp,
    float* __restrict__ ET, float* __restrict__ Dmat)
{
    const int tid = threadIdx.x;
    const int wave = tid >> 6, lane = tid & 63;
    const int z = blockIdx.z;
    const int r0w = blockIdx.x * 64 + wave * 16;
    const int m0 = blockIdx.y * 32;
    const unsigned short* Xh = z ? Xh_d : Xh_e;
    const unsigned short* Xl = z ? Xl_d : Xl_e;
    const unsigned short* Wh = z ? Wh_d : Wh_e;
    const unsigned short* Wl = z ? Wl_d : Wl_e;

    const int col = lane & 15;
    const int quad = lane >> 4;

    const unsigned short* pah = Xh + (long)(r0w + col) * 512 + quad * 8;
    const unsigned short* pal = Xl + (long)(r0w + col) * 512 + quad * 8;
    const long bofs = ((long)(m0 >> 4) << 13) + (quad << 7) + (col << 3);
    const unsigned short* pb0h = Wh + bofs;
    const unsigned short* pb0l = Wl + bofs;
    const unsigned short* pb1h = Wh + bofs + 8192;
    const unsigned short* pb1l = Wl + bofs + 8192;

    f32x4 a0h = {0.f,0.f,0.f,0.f}, a0x = {0.f,0.f,0.f,0.f};
    f32x4 a1h = {0.f,0.f,0.f,0.f}, a1x = {0.f,0.f,0.f,0.f};

    bf16x8 Ah = *(const bf16x8*)pah,  Al = *(const bf16x8*)pal;
    bf16x8 B0h = *(const bf16x8*)pb0h, B0l = *(const bf16x8*)pb0l;
    bf16x8 B1h = *(const bf16x8*)pb1h, B1l = *(const bf16x8*)pb1l;

#pragma unroll 1
    for (int k0 = 0; k0 < 512; k0 += 32) {
        bf16x8 nAh = Ah, nAl = Al, nB0h = B0h, nB0l = B0l, nB1h = B1h, nB1l = B1l;
        if (k0 + 32 < 512) {
            nAh = *(const bf16x8*)(pah + k0 + 32);
            nAl = *(const bf16x8*)(pal + k0 + 32);
            const long ko = (long)(k0 + 32) << 4;
            nB0h = *(const bf16x8*)(pb0h + ko);
            nB0l = *(const bf16x8*)(pb0l + ko);
            nB1h = *(const bf16x8*)(pb1h + ko);
            nB1l = *(const bf16x8*)(pb1l + ko);
        }
        a0h = __builtin_amdgcn_mfma_f32_16x16x32_bf16(Ah, B0h, a0h, 0, 0, 0);
        a1h = __builtin_amdgcn_mfma_f32_16x16x32_bf16(Ah, B1h, a1h, 0, 0, 0);
        a0x = __builtin_amdgcn_mfma_f32_16x16x32_bf16(Ah, B0l, a0x, 0, 0, 0);
        a1x = __builtin_amdgcn_mfma_f32_16x16x32_bf16(Ah, B1l, a1x, 0, 0, 0);
        a0x = __builtin_amdgcn_mfma_f32_16x16x32_bf16(Al, B0h, a0x, 0, 0, 0);
        a1x = __builtin_amdgcn_mfma_f32_16x16x32_bf16(Al, B1h, a1x, 0, 0, 0);
        Ah = nAh; Al = nAl; B0h = nB0h; B0l = nB0l; B1h = nB1h; B1l = nB1l;
    }

    if (z == 0) {
        const int batch = r0w >> 8;
        const int e0 = (r0w & 255) + quad * 4;
        float* base = ET + (long)batch * HDIM * ENC;
        float4 v;
        v.x = fast_exp2((a0h[0] + a0x[0]) * TANH_SCALE);
        v.y = fast_exp2((a0h[1] + a0x[1]) * TANH_SCALE);
        v.z = fast_exp2((a0h[2] + a0x[2]) * TANH_SCALE);
        v.w = fast_exp2((a0h[3] + a0x[3]) * TANH_SCALE);
        *(float4*)&base[(long)(m0 + col) * ENC + e0] = v;
        v.x = fast_exp2((a1h[0] + a1x[0]) * TANH_SCALE);
        v.y = fast_exp2((a1h[1] + a1x[1]) * TANH_SCALE);
        v.z = fast_exp2((a1h[2] + a1x[2]) * TANH_SCALE);
        v.w = fast_exp2((a1h[3] + a1x[3]) * TANH_SCALE);
        *(float4*)&base[(long)(m0 + 16 + col) * ENC + e0] = v;
    } else {
        const float bq0 = bmlp[m0 + col];
        const float bq1 = bmlp[m0 + 16 + col];
        const int r = r0w + quad * 4;
#pragma unroll
        for (int i = 0; i < 4; ++i) {
            Dmat[(long)(r + i) * HDIM + m0 + col] =
                fast_exp2((a0h[i] + a0x[i] + bq0) * TANH_SCALE);
            Dmat[(long)(r + i) * HDIM + m0 + 16 + col] =
                fast_exp2((a1h[i] + a1x[i] + bq1) * TANH_SCALE);
        }
    }
}

// ---------------------------------------------------------------------------
// FUSED attn+softmax+context v5: v3 structure (256 blocks x 512 thr, 4 rows)
// + de-lockstep rotation + deeper prefetch + vectorized phase 4.
// R4 lesson: 512 blocks doubled L2 traffic (per-block reads of full ET[b]/
// enc[b] slices are row-count-independent) -> revert to 256 blocks.
// New vs v3:
//  (a) wave->m-group and e-quarter rotated by blockIdx.x>>3: same-XCD blocks
//      stream ET/enc in different orders -> leaders' L3 misses not lockstep.
//  (b) ph2: prefetch depth 4; D/wo LDS reads as float2 (half the LDS instrs).
//  (c) ph4: thread = (4 consecutive h, e-quarter): float4 enc loads (1KB per
//      wave-instr, 4x fewer instrs), partials combined in LDS (aliases p8).
// ---------------------------------------------------------------------------
__global__ __launch_bounds__(512) void attn_ctx_kernel(
    const float* __restrict__ Dmat, const float* __restrict__ ET,
    const float* __restrict__ wo,
    const float* __restrict__ enc, const unsigned char* __restrict__ extm,
    float* __restrict__ attn_out, float* __restrict__ ctx)
{
    __shared__ __align__(16) float ds[4][HDIM];        // 8KB   D rows
    __shared__ __align__(16) float wos[HDIM];          // 2KB   W_out
    __shared__ __align__(16) float pbuf[8][4][ENC];    // 32KB  ph2 partials / ph4 partials
    __shared__ __align__(16) float as4T[ENC][4];       // 4KB   probs, transposed
    __shared__ float redm[4][4];
    __shared__ float reds[4][4];

    const int tid = threadIdx.x;
    const int b = blockIdx.z, d0 = blockIdx.x * 4;
    const long g0 = (long)b * DEC + d0;
    const int rot = blockIdx.x >> 3;   // same-XCD de-sync (blocks x, x+8,... differ)

    // ---- phase 1: stage D rows (4x512 contiguous = 8KB) + wo ----
    ((float4*)ds)[tid] = ((const float4*)(Dmat + g0 * HDIM))[tid];
    if (tid < 128) ((float4*)wos)[tid] = ((const float4*)wo)[tid];

    const int mg = ((tid >> 6) + rot) & 7;   // rotated wave -> m-group (bijective)
    const int e4 = (tid & 63) * 4;           // 4 consecutive e per thread
    const int mbase = mg * 64;
    const float* ep = ET + (long)b * HDIM * ENC + (long)mbase * ENC + e4;

    // prefetch depth 4 (global, independent of LDS)
    float4 Eb0 = *(const float4*)(ep);
    float4 Eb1 = *(const float4*)(ep + ENC);
    float4 Eb2 = *(const float4*)(ep + 2 * ENC);
    float4 Eb3 = *(const float4*)(ep + 3 * ENC);
    __syncthreads();

    // ---- phase 2: 64-m reduction, 4 e-cols x 4 rows per thread ----
    float acc[4][4] = {};             // [r][j]
    for (int i = 0; i < 64; i += 2) {
        float4 Ea = Eb0, Eb = Eb1;
        Eb0 = Eb2; Eb1 = Eb3;
        if (i + 4 < 64) {
            Eb2 = *(const float4*)(ep + (long)(i + 4) * ENC);
            Eb3 = *(const float4*)(ep + (long)(i + 5) * ENC);
        }
        const int m = mbase + i;
        const float2 w2 = *(const float2*)&wos[m];
#pragma unroll
        for (int r = 0; r < 4; ++r) {
            const float2 d2 = *(const float2*)&ds[r][m];
#pragma unroll
            for (int j = 0; j < 4; ++j) {
                float ea = ((const float*)&Ea)[j];
                float eb = ((const float*)&Eb)[j];
                acc[r][j] = fmaf(w2.x, fast_rcp(fmaf(ea, d2.x, 1.0f)), acc[r][j]);
                acc[r][j] = fmaf(w2.y, fast_rcp(fmaf(eb, d2.y, 1.0f)), acc[r][j]);
            }
        }
    }
#pragma unroll
    for (int r = 0; r < 4; ++r) {
        float4 v = make_float4(acc[r][0], acc[r][1], acc[r][2], acc[r][3]);
        *(float4*)&pbuf[mg][r][e4] = v;
    }
    __syncthreads();

    // ---- phase 3: combine + masks + softmax, ALL 8 waves (2 rows each) ----
    const int ty = tid >> 8;          // 0 -> rows {0,1}, 1 -> rows {2,3}
    const int e = tid & 255;
    const int wave = tid >> 6, lane = tid & 63;

    const bool pad = (enc[((long)b * ENC + e) * HDIM] == 0.0f);
    float l[2], p[2];
#pragma unroll
    for (int rl = 0; rl < 2; ++rl) {
        const int r = ty * 2 + rl;
        float a = 0.f;
#pragma unroll
        for (int q = 0; q < 8; ++q) a += pbuf[q][r][e];
        const bool xm = extm[(g0 + r) * ENC + e] != 0;
        l[rl] = (pad || xm) ? -__builtin_inff() : -2.0f * a;
    }
    float mx[2] = {l[0], l[1]};
#pragma unroll
    for (int off = 32; off >= 1; off >>= 1) {
#pragma unroll
        for (int rl = 0; rl < 2; ++rl)
            mx[rl] = fmaxf(mx[rl], __shfl_xor(mx[rl], off, 64));
    }
    if (lane == 0) {
        redm[ty * 2 + 0][wave & 3] = mx[0];
        redm[ty * 2 + 1][wave & 3] = mx[1];
    }
    __syncthreads();
    float s[2];
#pragma unroll
    for (int rl = 0; rl < 2; ++rl) {
        const int r = ty * 2 + rl;
        const float gm = fmaxf(fmaxf(redm[r][0], redm[r][1]),
                               fmaxf(redm[r][2], redm[r][3]));
        p[rl] = fast_exp2((l[rl] - gm) * LOG2E);
        s[rl] = p[rl];
    }
#pragma unroll
    for (int off = 32; off >= 1; off >>= 1) {
#pragma unroll
        for (int rl = 0; rl < 2; ++rl)
            s[rl] += __shfl_xor(s[rl], off, 64);
    }
    if (lane == 0) {
        reds[ty * 2 + 0][wave & 3] = s[0];
        reds[ty * 2 + 1][wave & 3] = s[1];
    }
    __syncthreads();
#pragma unroll
    for (int rl = 0; rl < 2; ++rl) {
        const int r = ty * 2 + rl;
        const float gs = reds[r][0] + reds[r][1] + reds[r][2] + reds[r][3];
        const float pr = p[rl] * fast_rcp(gs);
        attn_out[(g0 + r) * ENC + e] = pr;
        as4T[e][r] = pr;
    }
    __syncthreads();

    // ---- phase 4: ctx GEMV, thread = (4 h-cols, e-quarter); f4 enc loads ----
    float (*p4c)[4][HDIM] = (float (*)[4][HDIM])pbuf;   // [eq][r][h], 32KB alias

    const int hq = (tid & 127) * 4;                  // 0..508
    const int eq = ((tid >> 7) + rot) & 3;           // rotated e-quarter
    const int ebase = eq * 64;
    const float* ew = enc + (long)b * ENC * HDIM + (long)ebase * HDIM + hq;

    float4 Wb0 = *(const float4*)(ew);
    float4 Wb1 = *(const float4*)(ew + HDIM);
    float4 Wb2 = *(const float4*)(ew + 2 * HDIM);
    float4 Wb3 = *(const float4*)(ew + 3 * HDIM);

    float a4[4][4] = {};              // [r][j]
    for (int i = 0; i < 64; i += 2) {
        float4 Wa = Wb0, Wc = Wb1;
        Wb0 = Wb2; Wb1 = Wb3;
        if (i + 4 < 64) {
            Wb2 = *(const float4*)(ew + (long)(i + 4) * HDIM);
            Wb3 = *(const float4*)(ew + (long)(i + 5) * HDIM);
        }
        float4 pa = *(const float4*)&as4T[ebase + i][0];       // broadcast
        float4 pb = *(const float4*)&as4T[ebase + i + 1][0];
#pragma unroll
        for (int r = 0; r < 4; ++r) {
            const float par = ((const float*)&pa)[r];
            const float pbr = ((const float*)&pb)[r];
#pragma unroll
            for (int j = 0; j < 4; ++j) {
                a4[r][j] = fmaf(par, ((const float*)&Wa)[j], a4[r][j]);
                a4[r][j] = fmaf(pbr, ((const float*)&Wc)[j], a4[r][j]);
            }
        }
    }
#pragma unroll
    for (int r = 0; r < 4; ++r)
        *(float4*)&p4c[eq][r][hq] = make_float4(a4[r][0], a4[r][1], a4[r][2], a4[r][3]);
    __syncthreads();

    // final combine: thread = h
    const int h = tid;
#pragma unroll
    for (int r = 0; r < 4; ++r) {
        const float o = p4c[0][r][h] + p4c[1][r][h] + p4c[2][r][h] + p4c[3][r][h];
        ctx[(g0 + r) * HDIM + h] = o;
    }
}

// ---------------------------------------------------------------------------
extern "C" void kernel_launch(void* const* d_in, const int* in_sizes, int n_in,
                              void* d_out, int out_size, void* d_ws, size_t ws_size,
                              hipStream_t stream) {
    const float* dec = (const float*)d_in[0];
    const float* enc = (const float*)d_in[1];
    const unsigned char* extm = (const unsigned char*)d_in[2];
    const float* Wmlp = (const float*)d_in[3];
    const float* bmlp = (const float*)d_in[4];
    const float* Wout = (const float*)d_in[5];
    // d_in[6] = b_out: additive constant, cancels in softmax

    float* ctx = (float*)d_out;                    // [B, DEC, H]
    float* attn = ctx + (size_t)B * DEC * HDIM;    // [B, DEC, ENC]

    const size_t F = (size_t)B * DEC * HDIM;       // 524288
    float* ET = (float*)d_ws;                      // [B][H][ENC] fp32
    float* Dmat = ET + F;                          // [B*DEC][H] fp32
    unsigned short* Xh_e = (unsigned short*)(Dmat + F);
    unsigned short* Xl_e = Xh_e + F;
    unsigned short* Xh_d = Xl_e + F;
    unsigned short* Xl_d = Xh_d + F;
    unsigned short* Wh_e = Xl_d + F;               // blocked-T layout, 512*512
    unsigned short* Wl_e = Wh_e + HDIM * HDIM;
    unsigned short* Wh_d = Wl_e + HDIM * HDIM;
    unsigned short* Wl_d = Wh_d + HDIM * HDIM;

    convert_kernel<<<dim3(256, 1, 4), 256, 0, stream>>>(
        enc, dec, Wmlp, Xh_e, Xl_e, Xh_d, Xl_d, Wh_e, Wl_e, Wh_d, Wl_d);
    proj_mfma_kernel<<<dim3(16, 16, 2), 256, 0, stream>>>(
        Xh_e, Xl_e, Xh_d, Xl_d, Wh_e, Wl_e, Wh_d, Wl_d, bmlp, ET, Dmat);
    attn_ctx_kernel<<<dim3(DEC / 4, 1, B), 512, 0, stream>>>(
        Dmat, ET, Wout, enc, extm, attn, ctx);
}

// Round 6
// 108.388 us; speedup vs baseline: 1.1326x; 1.0233x over previous
//
#include <hip/hip_runtime.h>
#include <math.h>

#define B 4
#define DEC 256
#define ENC 256
#define HDIM 512

// exp2(x*TANH_SCALE) == e^{2x};  tanh(x) = 1 - 2/(1+e^{2x})
#define TANH_SCALE 2.8853900817779268f
#define LOG2E 1.4426950408889634f

__device__ __forceinline__ float fast_exp2(float x) { return __builtin_amdgcn_exp2f(x); }
__device__ __forceinline__ float fast_rcp(float x)  { return __builtin_amdgcn_rcpf(x); }

typedef __attribute__((ext_vector_type(8))) short bf16x8;   // 8 bf16 = 4 VGPR
typedef __attribute__((ext_vector_type(4))) short bf16x4;
typedef __attribute__((ext_vector_type(4))) float f32x4;

__device__ __forceinline__ unsigned short bf16_rne(float x) {
    unsigned u = __float_as_uint(x);
    return (unsigned short)((u + 0x7FFFu + ((u >> 16) & 1u)) >> 16);
}
__device__ __forceinline__ float bf16_to_f(unsigned short h) {
    return __uint_as_float((unsigned)h << 16);
}

// Blocked-transpose W layout (shorts): ofs(m,k) = (m/16)*8192 + (k/8)*128 + (m%16)*8 + k%8
#define W_OFS(m, k) ((((long)(m) >> 4) << 13) + (((long)(k) >> 3) << 7) + (((m) & 15) << 3) + ((k) & 7))

// ---------------------------------------------------------------------------
// convert: fp32 -> bf16 hi/lo split. (unchanged)
// ---------------------------------------------------------------------------
__global__ __launch_bounds__(256) void convert_kernel(
    const float* __restrict__ enc, const float* __restrict__ dec,
    const float* __restrict__ Wmlp,
    unsigned short* __restrict__ Xh_e, unsigned short* __restrict__ Xl_e,
    unsigned short* __restrict__ Xh_d, unsigned short* __restrict__ Xl_d,
    unsigned short* __restrict__ Wh_e, unsigned short* __restrict__ Wl_e,
    unsigned short* __restrict__ Wh_d, unsigned short* __restrict__ Wl_d)
{
    const int tid = threadIdx.x, z = blockIdx.z;
    if (z < 2) {
        const float* X = z ? dec : enc;
        unsigned short* H = z ? Xh_d : Xh_e;
        unsigned short* L = z ? Xl_d : Xl_e;
        const long i8 = ((long)blockIdx.x * 256 + tid) * 8;
        float4 v0 = *(const float4*)(X + i8);
        float4 v1 = *(const float4*)(X + i8 + 4);
        float xs[8] = {v0.x, v0.y, v0.z, v0.w, v1.x, v1.y, v1.z, v1.w};
        bf16x8 hv, lv;
#pragma unroll
        for (int j = 0; j < 8; ++j) {
            unsigned short h = bf16_rne(xs[j]);
            hv[j] = (short)h;
            lv[j] = (short)bf16_rne(xs[j] - bf16_to_f(h));
        }
        *(bf16x8*)(H + i8) = hv;
        *(bf16x8*)(L + i8) = lv;
    } else {
        const float* Wsrc = Wmlp + (z == 3 ? (long)HDIM * HDIM : 0);
        unsigned short* H = (z == 3) ? Wh_d : Wh_e;
        unsigned short* L = (z == 3) ? Wl_d : Wl_e;
        const int t = blockIdx.x * 256 + tid;     // 0..65535
        const int m = t & 511;
        const int k0 = (t >> 9) << 2;             // multiple of 4
        bf16x4 hv, lv;
#pragma unroll
        for (int j = 0; j < 4; ++j) {
            float x = Wsrc[(long)(k0 + j) * 512 + m];   // coalesced reads
            unsigned short h = bf16_rne(x);
            hv[j] = (short)h;
            lv[j] = (short)bf16_rne(x - bf16_to_f(h));
        }
        const long ofs = W_OFS(m, k0);            // 4 consecutive shorts
        *(bf16x4*)(H + ofs) = hv;
        *(bf16x4*)(L + ofs) = lv;
    }
}

// ---------------------------------------------------------------------------
// proj via MFMA (unchanged): wave = 16 r x 32 m, block = 64 r x 32 m.
// ---------------------------------------------------------------------------
__global__ __launch_bounds__(256) void proj_mfma_kernel(
    const unsigned short* __restrict__ Xh_e, const unsigned short* __restrict__ Xl_e,
    const unsigned short* __restrict__ Xh_d, const unsigned short* __restrict__ Xl_d,
    const unsigned short* __restrict__ Wh_e, const unsigned short* __restrict__ Wl_e,
    const unsigned short* __restrict__ Wh_d, const unsigned short* __restrict__ Wl_d,
    const float* __restrict__ bmlp,
    float* __restrict__ ET, float* __restrict__ Dmat)
{
    const int tid = threadIdx.x;
    const int wave = tid >> 6, lane = tid & 63;
    const int z = blockIdx.z;
    const int r0w = blockIdx.x * 64 + wave * 16;
    const int m0 = blockIdx.y * 32;
    const unsigned short* Xh = z ? Xh_d : Xh_e;
    const unsigned short* Xl = z ? Xl_d : Xl_e;
    const unsigned short* Wh = z ? Wh_d : Wh_e;
    const unsigned short* Wl = z ? Wl_d : Wl_e;

    const int col = lane & 15;
    const int quad = lane >> 4;

    const unsigned short* pah = Xh + (long)(r0w + col) * 512 + quad * 8;
    const unsigned short* pal = Xl + (long)(r0w + col) * 512 + quad * 8;
    const long bofs = ((long)(m0 >> 4) << 13) + (quad << 7) + (col << 3);
    const unsigned short* pb0h = Wh + bofs;
    const unsigned short* pb0l = Wl + bofs;
    const unsigned short* pb1h = Wh + bofs + 8192;
    const unsigned short* pb1l = Wl + bofs + 8192;

    f32x4 a0h = {0.f,0.f,0.f,0.f}, a0x = {0.f,0.f,0.f,0.f};
    f32x4 a1h = {0.f,0.f,0.f,0.f}, a1x = {0.f,0.f,0.f,0.f};

    bf16x8 Ah = *(const bf16x8*)pah,  Al = *(const bf16x8*)pal;
    bf16x8 B0h = *(const bf16x8*)pb0h, B0l = *(const bf16x8*)pb0l;
    bf16x8 B1h = *(const bf16x8*)pb1h, B1l = *(const bf16x8*)pb1l;

#pragma unroll 1
    for (int k0 = 0; k0 < 512; k0 += 32) {
        bf16x8 nAh = Ah, nAl = Al, nB0h = B0h, nB0l = B0l, nB1h = B1h, nB1l = B1l;
        if (k0 + 32 < 512) {
            nAh = *(const bf16x8*)(pah + k0 + 32);
            nAl = *(const bf16x8*)(pal + k0 + 32);
            const long ko = (long)(k0 + 32) << 4;
            nB0h = *(const bf16x8*)(pb0h + ko);
            nB0l = *(const bf16x8*)(pb0l + ko);
            nB1h = *(const bf16x8*)(pb1h + ko);
            nB1l = *(const bf16x8*)(pb1l + ko);
        }
        a0h = __builtin_amdgcn_mfma_f32_16x16x32_bf16(Ah, B0h, a0h, 0, 0, 0);
        a1h = __builtin_amdgcn_mfma_f32_16x16x32_bf16(Ah, B1h, a1h, 0, 0, 0);
        a0x = __builtin_amdgcn_mfma_f32_16x16x32_bf16(Ah, B0l, a0x, 0, 0, 0);
        a1x = __builtin_amdgcn_mfma_f32_16x16x32_bf16(Ah, B1l, a1x, 0, 0, 0);
        a0x = __builtin_amdgcn_mfma_f32_16x16x32_bf16(Al, B0h, a0x, 0, 0, 0);
        a1x = __builtin_amdgcn_mfma_f32_16x16x32_bf16(Al, B1h, a1x, 0, 0, 0);
        Ah = nAh; Al = nAl; B0h = nB0h; B0l = nB0l; B1h = nB1h; B1l = nB1l;
    }

    if (z == 0) {
        const int batch = r0w >> 8;
        const int e0 = (r0w & 255) + quad * 4;
        float* base = ET + (long)batch * HDIM * ENC;
        float4 v;
        v.x = fast_exp2((a0h[0] + a0x[0]) * TANH_SCALE);
        v.y = fast_exp2((a0h[1] + a0x[1]) * TANH_SCALE);
        v.z = fast_exp2((a0h[2] + a0x[2]) * TANH_SCALE);
        v.w = fast_exp2((a0h[3] + a0x[3]) * TANH_SCALE);
        *(float4*)&base[(long)(m0 + col) * ENC + e0] = v;
        v.x = fast_exp2((a1h[0] + a1x[0]) * TANH_SCALE);
        v.y = fast_exp2((a1h[1] + a1x[1]) * TANH_SCALE);
        v.z = fast_exp2((a1h[2] + a1x[2]) * TANH_SCALE);
        v.w = fast_exp2((a1h[3] + a1x[3]) * TANH_SCALE);
        *(float4*)&base[(long)(m0 + 16 + col) * ENC + e0] = v;
    } else {
        const float bq0 = bmlp[m0 + col];
        const float bq1 = bmlp[m0 + 16 + col];
        const int r = r0w + quad * 4;
#pragma unroll
        for (int i = 0; i < 4; ++i) {
            Dmat[(long)(r + i) * HDIM + m0 + col] =
                fast_exp2((a0h[i] + a0x[i] + bq0) * TANH_SCALE);
            Dmat[(long)(r + i) * HDIM + m0 + 16 + col] =
                fast_exp2((a1h[i] + a1x[i] + bq1) * TANH_SCALE);
        }
    }
}

// ---------------------------------------------------------------------------
// FUSED attn+softmax+context v6: v5 structure + DEPTH-8 ring prefetch.
// R5 calibration: total = 80.5us const + attn_ctx; v5 attn_ctx ~= 30.4us vs
// ~12us issue floor -> ~18us latency exposure.  v5 prefetch depth (4 rows ~=
// 256cy of compute cover) < L2/L3 latency (200-600cy) at only 2 waves/SIMD.
// v6: both streaming loops (ph2 ET rows, ph4 enc rows) hold 8 float4 rows in
// flight (32 VGPR ring), process 4 rows/iter -> load-to-use distance ~=
// 2 iters ~= 512cy of trans/VALU work per wave.  LDS reads widened to f4.
// ---------------------------------------------------------------------------
__global__ __launch_bounds__(512) void attn_ctx_kernel(
    const float* __restrict__ Dmat, const float* __restrict__ ET,
    const float* __restrict__ wo,
    const float* __restrict__ enc, const unsigned char* __restrict__ extm,
    float* __restrict__ attn_out, float* __restrict__ ctx)
{
    __shared__ __align__(16) float ds[4][HDIM];        // 8KB   D rows
    __shared__ __align__(16) float wos[HDIM];          // 2KB   W_out
    __shared__ __align__(16) float pbuf[8][4][ENC];    // 32KB  ph2 partials / ph4 partials
    __shared__ __align__(16) float as4T[ENC][4];       // 4KB   probs, transposed
    __shared__ float redm[4][4];
    __shared__ float reds[4][4];

    const int tid = threadIdx.x;
    const int b = blockIdx.z, d0 = blockIdx.x * 4;
    const long g0 = (long)b * DEC + d0;
    const int rot = blockIdx.x >> 3;   // same-XCD de-sync (blocks x, x+8,... differ)

    // ---- phase 1: stage D rows (4x512 contiguous = 8KB) + wo ----
    ((float4*)ds)[tid] = ((const float4*)(Dmat + g0 * HDIM))[tid];
    if (tid < 128) ((float4*)wos)[tid] = ((const float4*)wo)[tid];

    const int mg = ((tid >> 6) + rot) & 7;   // rotated wave -> m-group (bijective)
    const int e4 = (tid & 63) * 4;           // 4 consecutive e per thread
    const int mbase = mg * 64;
    const float* ep = ET + (long)b * HDIM * ENC + (long)mbase * ENC + e4;

    // ring prefetch: 8 rows in flight (issued before the stage barrier)
    float4 rb[8];
#pragma unroll
    for (int j = 0; j < 8; ++j) rb[j] = *(const float4*)(ep + (long)j * ENC);
    __syncthreads();

    // ---- phase 2: 64-m reduction, 4 e-cols x 4 rows/thread, 4 m per iter ----
    float acc[4][4] = {};             // [r][j]
    for (int i = 0; i < 64; i += 4) {
        float4 c0 = rb[0], c1 = rb[1], c2 = rb[2], c3 = rb[3];
        rb[0] = rb[4]; rb[1] = rb[5]; rb[2] = rb[6]; rb[3] = rb[7];
        if (i + 8 < 64) {
#pragma unroll
            for (int j = 0; j < 4; ++j)
                rb[4 + j] = *(const float4*)(ep + (long)(i + 8 + j) * ENC);
        }
        const int m = mbase + i;
        const float4 w4 = *(const float4*)&wos[m];
#pragma unroll
        for (int r = 0; r < 4; ++r) {
            const float4 d4 = *(const float4*)&ds[r][m];
#pragma unroll
            for (int j = 0; j < 4; ++j) {
                acc[r][j] = fmaf(w4.x, fast_rcp(fmaf(((const float*)&c0)[j], d4.x, 1.0f)), acc[r][j]);
                acc[r][j] = fmaf(w4.y, fast_rcp(fmaf(((const float*)&c1)[j], d4.y, 1.0f)), acc[r][j]);
                acc[r][j] = fmaf(w4.z, fast_rcp(fmaf(((const float*)&c2)[j], d4.z, 1.0f)), acc[r][j]);
                acc[r][j] = fmaf(w4.w, fast_rcp(fmaf(((const float*)&c3)[j], d4.w, 1.0f)), acc[r][j]);
            }
        }
    }
#pragma unroll
    for (int r = 0; r < 4; ++r) {
        float4 v = make_float4(acc[r][0], acc[r][1], acc[r][2], acc[r][3]);
        *(float4*)&pbuf[mg][r][e4] = v;
    }
    __syncthreads();

    // ---- phase 3: combine + masks + softmax, ALL 8 waves (2 rows each) ----
    const int ty = tid >> 8;          // 0 -> rows {0,1}, 1 -> rows {2,3}
    const int e = tid & 255;
    const int wave = tid >> 6, lane = tid & 63;

    const bool pad = (enc[((long)b * ENC + e) * HDIM] == 0.0f);
    float l[2], p[2];
#pragma unroll
    for (int rl = 0; rl < 2; ++rl) {
        const int r = ty * 2 + rl;
        float a = 0.f;
#pragma unroll
        for (int q = 0; q < 8; ++q) a += pbuf[q][r][e];
        const bool xm = extm[(g0 + r) * ENC + e] != 0;
        l[rl] = (pad || xm) ? -__builtin_inff() : -2.0f * a;
    }
    float mx[2] = {l[0], l[1]};
#pragma unroll
    for (int off = 32; off >= 1; off >>= 1) {
#pragma unroll
        for (int rl = 0; rl < 2; ++rl)
            mx[rl] = fmaxf(mx[rl], __shfl_xor(mx[rl], off, 64));
    }
    if (lane == 0) {
        redm[ty * 2 + 0][wave & 3] = mx[0];
        redm[ty * 2 + 1][wave & 3] = mx[1];
    }
    __syncthreads();
    float s[2];
#pragma unroll
    for (int rl = 0; rl < 2; ++rl) {
        const int r = ty * 2 + rl;
        const float gm = fmaxf(fmaxf(redm[r][0], redm[r][1]),
                               fmaxf(redm[r][2], redm[r][3]));
        p[rl] = fast_exp2((l[rl] - gm) * LOG2E);
        s[rl] = p[rl];
    }
#pragma unroll
    for (int off = 32; off >= 1; off >>= 1) {
#pragma unroll
        for (int rl = 0; rl < 2; ++rl)
            s[rl] += __shfl_xor(s[rl], off, 64);
    }
    if (lane == 0) {
        reds[ty * 2 + 0][wave & 3] = s[0];
        reds[ty * 2 + 1][wave & 3] = s[1];
    }
    __syncthreads();
#pragma unroll
    for (int rl = 0; rl < 2; ++rl) {
        const int r = ty * 2 + rl;
        const float gs = reds[r][0] + reds[r][1] + reds[r][2] + reds[r][3];
        const float pr = p[rl] * fast_rcp(gs);
        attn_out[(g0 + r) * ENC + e] = pr;
        as4T[e][r] = pr;
    }
    __syncthreads();

    // ---- phase 4: ctx GEMV, thread = (4 h-cols, e-quarter); depth-8 ring ----
    float (*p4c)[4][HDIM] = (float (*)[4][HDIM])pbuf;   // [eq][r][h], 32KB alias

    const int hq = (tid & 127) * 4;                  // 0..508
    const int eq = ((tid >> 7) + rot) & 3;           // rotated e-quarter
    const int ebase = eq * 64;
    const float* ew = enc + (long)b * ENC * HDIM + (long)ebase * HDIM + hq;

    float4 wb[8];
#pragma unroll
    for (int j = 0; j < 8; ++j) wb[j] = *(const float4*)(ew + (long)j * HDIM);

    float a4[4][4] = {};              // [r][j]
    for (int i = 0; i < 64; i += 4) {
        float4 c0 = wb[0], c1 = wb[1], c2 = wb[2], c3 = wb[3];
        wb[0] = wb[4]; wb[1] = wb[5]; wb[2] = wb[6]; wb[3] = wb[7];
        if (i + 8 < 64) {
#pragma unroll
            for (int j = 0; j < 4; ++j)
                wb[4 + j] = *(const float4*)(ew + (long)(i + 8 + j) * HDIM);
        }
        float4 pa = *(const float4*)&as4T[ebase + i][0];       // broadcast b128
        float4 pb = *(const float4*)&as4T[ebase + i + 1][0];
        float4 pc = *(const float4*)&as4T[ebase + i + 2][0];
        float4 pd = *(const float4*)&as4T[ebase + i + 3][0];
#pragma unroll
        for (int r = 0; r < 4; ++r) {
            const float par = ((const float*)&pa)[r];
            const float pbr = ((const float*)&pb)[r];
            const float pcr = ((const float*)&pc)[r];
            const float pdr = ((const float*)&pd)[r];
#pragma unroll
            for (int j = 0; j < 4; ++j) {
                a4[r][j] = fmaf(par, ((const float*)&c0)[j], a4[r][j]);
                a4[r][j] = fmaf(pbr, ((const float*)&c1)[j], a4[r][j]);
                a4[r][j] = fmaf(pcr, ((const float*)&c2)[j], a4[r][j]);
                a4[r][j] = fmaf(pdr, ((const float*)&c3)[j], a4[r][j]);
            }
        }
    }
#pragma unroll
    for (int r = 0; r < 4; ++r)
        *(float4*)&p4c[eq][r][hq] = make_float4(a4[r][0], a4[r][1], a4[r][2], a4[r][3]);
    __syncthreads();

    // final combine: thread = h
    const int h = tid;
#pragma unroll
    for (int r = 0; r < 4; ++r) {
        const float o = p4c[0][r][h] + p4c[1][r][h] + p4c[2][r][h] + p4c[3][r][h];
        ctx[(g0 + r) * HDIM + h] = o;
    }
}

// ---------------------------------------------------------------------------
extern "C" void kernel_launch(void* const* d_in, const int* in_sizes, int n_in,
                              void* d_out, int out_size, void* d_ws, size_t ws_size,
                              hipStream_t stream) {
    const float* dec = (const float*)d_in[0];
    const float* enc = (const float*)d_in[1];
    const unsigned char* extm = (const unsigned char*)d_in[2];
    const float* Wmlp = (const float*)d_in[3];
    const float* bmlp = (const float*)d_in[4];
    const float* Wout = (const float*)d_in[5];
    // d_in[6] = b_out: additive constant, cancels in softmax

    float* ctx = (float*)d_out;                    // [B, DEC, H]
    float* attn = ctx + (size_t)B * DEC * HDIM;    // [B, DEC, ENC]

    const size_t F = (size_t)B * DEC * HDIM;       // 524288
    float* ET = (float*)d_ws;                      // [B][H][ENC] fp32
    float* Dmat = ET + F;                          // [B*DEC][H] fp32
    unsigned short* Xh_e = (unsigned short*)(Dmat + F);
    unsigned short* Xl_e = Xh_e + F;
    unsigned short* Xh_d = Xl_e + F;
    unsigned short* Xl_d = Xh_d + F;
    unsigned short* Wh_e = Xl_d + F;               // blocked-T layout, 512*512
    unsigned short* Wl_e = Wh_e + HDIM * HDIM;
    unsigned short* Wh_d = Wl_e + HDIM * HDIM;
    unsigned short* Wl_d = Wh_d + HDIM * HDIM;

    convert_kernel<<<dim3(256, 1, 4), 256, 0, stream>>>(
        enc, dec, Wmlp, Xh_e, Xl_e, Xh_d, Xl_d, Wh_e, Wl_e, Wh_d, Wl_d);
    proj_mfma_kernel<<<dim3(16, 16, 2), 256, 0, stream>>>(
        Xh_e, Xl_e, Xh_d, Xl_d, Wh_e, Wl_e, Wh_d, Wl_d, bmlp, ET, Dmat);
    attn_ctx_kernel<<<dim3(DEC / 4, 1, B), 512, 0, stream>>>(
        Dmat, ET, Wout, enc, extm, attn, ctx);
}